// Round 2
// baseline (393.670 us; speedup 1.0000x reference)
//
#include <hip/hip_runtime.h>
#include <math.h>

#define BS   8
#define CLS  4
#define CCH  256
#define HH   128
#define WW   128
#define HWSZ (HH * WW)   // 16384
#define LL   19
#define TKK  256
#define MHH  64
#define MWW  64

// ---------------------------------------------------------------------------
// Fused prep kernel, one block per (b,l):
//   tq[t]       = sum_c token[b,l,c] * W2[t,c]          (thread = t, in LDS)
//   t3t[b,o,l]  = sum_t token[b,l,t] * W3[o,t] + b3[o]  (thread = o; row pad 20)
//   u[b,l,c]    = (1/64) * sum_t W1[t,c] * tq[t]        (thread = c)
// 1/64 folds the cls-mean (1/4) and softmax scale (1/sqrt(256)=1/16).
// ---------------------------------------------------------------------------
__global__ __launch_bounds__(256) void k_prep(
    const float* __restrict__ token, const float* __restrict__ W1,
    const float* __restrict__ W2, const float* __restrict__ W3,
    const float* __restrict__ b3, float* __restrict__ u,
    float* __restrict__ t3t) {
  __shared__ float tok_s[TKK];
  __shared__ float tq_s[TKK];
  const int bl = blockIdx.x;           // b*LL + l
  const int b  = bl / LL;
  const int l  = bl - b * LL;
  const int t  = threadIdx.x;
  tok_s[t] = token[(size_t)bl * TKK + t];
  __syncthreads();
  const float4* w2r = (const float4*)(W2 + (size_t)t * TKK);
  const float4* w3r = (const float4*)(W3 + (size_t)t * TKK);
  float a2 = 0.f, a3 = 0.f;
#pragma unroll 8
  for (int i = 0; i < TKK / 4; ++i) {
    float4 x = w2r[i];
    float4 y = w3r[i];
    const float* ts = &tok_s[4 * i];
    a2 += x.x * ts[0] + x.y * ts[1] + x.z * ts[2] + x.w * ts[3];
    a3 += y.x * ts[0] + y.y * ts[1] + y.z * ts[2] + y.w * ts[3];
  }
  tq_s[t] = a2;
  t3t[((size_t)b * CCH + t) * 20 + l] = a3 + b3[t];
  __syncthreads();
  float s0 = 0.f, s1 = 0.f, s2 = 0.f, s3 = 0.f;
#pragma unroll 4
  for (int k = 0; k < TKK; k += 4) {
    s0 += W1[(k + 0) * CCH + t] * tq_s[k + 0];
    s1 += W1[(k + 1) * CCH + t] * tq_s[k + 1];
    s2 += W1[(k + 2) * CCH + t] * tq_s[k + 2];
    s3 += W1[(k + 3) * CCH + t] * tq_s[k + 3];
  }
  u[(size_t)bl * CCH + t] = (s0 + s1 + s2 + s3) * (1.0f / 64.0f);
}

// ---------------------------------------------------------------------------
// Main fused kernel. Block = (b, one 128-pixel image row). 256 thr = 4 waves.
// Wave wv owns channel slice [wv*64, wv*64+64); lane owns pixel pair (2i,2i+1)
// -> float2 global loads; the pair shares one nearest-upsampled mask value.
//   phase 1: q = mix of 4 fea batches * mask; facc[l] += q * u  (u LDS b128
//            broadcast); ds_add_f32 reduce into acc_s[19][128]
//   softmax in-place in acc_s (threads 0..127, lane-consecutive = free)
//   phase 4: wave wv owns o-slice; t3 read via wave-uniform scalar loads from
//            global (t3t rows, 80 B aligned); out = p.t3 + fea, float2 stores
// LDS: u_s 19456 + acc_s 9728 = 29184 B -> 5 blocks/CU (grid gives 4 = 50%)
// ---------------------------------------------------------------------------
__global__ __launch_bounds__(256, 4) void k_main(
    const float* __restrict__ mask, const float* __restrict__ fea,
    const float* __restrict__ u, const float* __restrict__ t3t,
    float* __restrict__ out) {
  __shared__ float u_s[LL][CCH];     // [l][c]
  __shared__ float acc_s[LL][128];   // logits -> probs, [l][pix]

  const int blk  = blockIdx.x;
  const int b    = blk & 7;          // b fastest: blocks sharing fea adjacent
  const int tile = blk >> 3;         // 0..127 = image row
  const int n0   = tile * WW;
  const int t    = threadIdx.x;
  const int lane = t & 63;
  const int wv   = t >> 6;

  // stage u (coalesced) + zero the accumulator
#pragma unroll
  for (int l = 0; l < LL; ++l) u_s[l][t] = u[((size_t)b * LL + l) * CCH + t];
  for (int k = t; k < LL * 128; k += 256) ((float*)acc_s)[k] = 0.f;

  // mask value shared by the lane's pixel pair: row tile/2, col lane
  const int hrow = tile >> 1;
  const float m0 = mask[(((size_t)(b * CLS + 0)) * MHH + hrow) * MWW + lane];
  const float m1 = mask[(((size_t)(b * CLS + 1)) * MHH + hrow) * MWW + lane];
  const float m2 = mask[(((size_t)(b * CLS + 2)) * MHH + hrow) * MWW + lane];
  const float m3 = mask[(((size_t)(b * CLS + 3)) * MHH + hrow) * MWW + lane];

  __syncthreads();

  // fea batch indices: (4b+cl) % 8 == 4*(b&1) + cl
  const int f0 = (b & 1) * 4;
  const float* fb0 = fea + (size_t)(f0 + 0) * CCH * HWSZ + n0;
  const float* fb1 = fea + (size_t)(f0 + 1) * CCH * HWSZ + n0;
  const float* fb2 = fea + (size_t)(f0 + 2) * CCH * HWSZ + n0;
  const float* fb3 = fea + (size_t)(f0 + 3) * CCH * HWSZ + n0;

  float facc[LL][2];
#pragma unroll
  for (int l = 0; l < LL; ++l) { facc[l][0] = 0.f; facc[l][1] = 0.f; }

  const int c0 = wv * 64;
#pragma unroll 1
  for (int cc = 0; cc < 64; cc += 4) {
    float2 q[4];
#pragma unroll
    for (int j = 0; j < 4; ++j) {
      const size_t coff = (size_t)(c0 + cc + j) * HWSZ;
      const float2 v0 = ((const float2*)(fb0 + coff))[lane];
      const float2 v1 = ((const float2*)(fb1 + coff))[lane];
      const float2 v2 = ((const float2*)(fb2 + coff))[lane];
      const float2 v3 = ((const float2*)(fb3 + coff))[lane];
      q[j].x = v0.x * m0 + v1.x * m1 + v2.x * m2 + v3.x * m3;
      q[j].y = v0.y * m0 + v1.y * m1 + v2.y * m2 + v3.y * m3;
    }
#pragma unroll
    for (int l = 0; l < LL; ++l) {
      const float4 uu = *(const float4*)&u_s[l][c0 + cc];  // uniform broadcast
      facc[l][0] += q[0].x * uu.x + q[1].x * uu.y + q[2].x * uu.z + q[3].x * uu.w;
      facc[l][1] += q[0].y * uu.x + q[1].y * uu.y + q[2].y * uu.z + q[3].y * uu.w;
    }
  }

  // cross-wave reduction: distinct addresses within a wave, 4-way across waves
#pragma unroll
  for (int l = 0; l < LL; ++l) {
    atomicAdd(&acc_s[l][2 * lane + 0], facc[l][0]);
    atomicAdd(&acc_s[l][2 * lane + 1], facc[l][1]);
  }
  __syncthreads();

  // softmax over l, in-place (threads 0..127, one pixel each; stride-1 = free)
  if (t < 128) {
    float a[LL];
    float mx = -INFINITY;
#pragma unroll
    for (int l = 0; l < LL; ++l) { a[l] = acc_s[l][t]; mx = fmaxf(mx, a[l]); }
    float e[LL];
    float sum = 0.f;
#pragma unroll
    for (int l = 0; l < LL; ++l) { e[l] = __expf(a[l] - mx); sum += e[l]; }
    const float inv = 1.0f / sum;
#pragma unroll
    for (int l = 0; l < LL; ++l)
      acc_s[l][t] = (a[l] != 0.f) ? e[l] * inv : 0.f;  // replicate where(a!=0)
  }
  __syncthreads();

  // probs for this lane's pixel pair
  float2 p[LL];
#pragma unroll
  for (int l = 0; l < LL; ++l) p[l] = *(const float2*)&acc_s[l][2 * lane];

  // phase 4: wave-uniform o-slice; t3 rows via scalar loads
  const int wvu = __builtin_amdgcn_readfirstlane(wv);
  const int ob  = wvu * 64;
#pragma unroll 2
  for (int i = 0; i < 64; ++i) {
    const int o = ob + i;
    const float* tr = t3t + ((size_t)b * CCH + o) * 20;  // uniform -> s_load
    float sx = 0.f, sy = 0.f;
#pragma unroll
    for (int l = 0; l < LL; ++l) {
      const float tv = tr[l];
      sx += p[l].x * tv;
      sy += p[l].y * tv;
    }
    const size_t off = ((size_t)b * CCH + o) * HWSZ + n0;
    const float2 r = ((const float2*)(fea + off))[lane];
    float2 res;
    res.x = sx + r.x;
    res.y = sy + r.y;
    ((float2*)(out + off))[lane] = res;
  }
}

// ---------------------------------------------------------------------------
extern "C" void kernel_launch(void* const* d_in, const int* in_sizes, int n_in,
                              void* d_out, int out_size, void* d_ws, size_t ws_size,
                              hipStream_t stream) {
  (void)in_sizes; (void)n_in; (void)out_size; (void)ws_size;
  const float* mask  = (const float*)d_in[0];
  const float* fea   = (const float*)d_in[1];
  const float* token = (const float*)d_in[2];
  const float* W1    = (const float*)d_in[3];
  const float* W2    = (const float*)d_in[4];
  const float* W3    = (const float*)d_in[5];
  const float* b3    = (const float*)d_in[6];
  float* out = (float*)d_out;

  float* u   = (float*)d_ws;                 // BS*LL*CCH floats (38912)
  float* t3t = u + BS * LL * CCH;            // BS*CCH*20 floats (40960)

  k_prep<<<BS * LL, 256, 0, stream>>>(token, W1, W2, W3, b3, u, t3t);
  k_main<<<(HWSZ / WW) * BS, 256, 0, stream>>>(mask, fea, u, t3t, out);
}

// Round 3
// 370.309 us; speedup vs baseline: 1.0631x; 1.0631x over previous
//
#include <hip/hip_runtime.h>
#include <math.h>

#define BS   8
#define CLS  4
#define CCH  256
#define HH   128
#define WW   128
#define HWSZ (HH * WW)   // 16384
#define LL   19
#define TKK  256
#define MHH  64
#define MWW  64

// ---------------------------------------------------------------------------
// Fused prep kernel, one block per (b,l):
//   tq[t]       = sum_c token[b,l,c] * W2[t,c]          (thread = t, in LDS)
//   t3t[b,o,l]  = sum_t token[b,l,t] * W3[o,t] + b3[o]  (thread = o; row pad 20)
//   u[b,l,c]    = (1/64) * sum_t W1[t,c] * tq[t]        (thread = c)
// 1/64 folds the cls-mean (1/4) and softmax scale (1/sqrt(256)=1/16).
// ---------------------------------------------------------------------------
__global__ __launch_bounds__(256) void k_prep(
    const float* __restrict__ token, const float* __restrict__ W1,
    const float* __restrict__ W2, const float* __restrict__ W3,
    const float* __restrict__ b3, float* __restrict__ u,
    float* __restrict__ t3t) {
  __shared__ float tok_s[TKK];
  __shared__ float tq_s[TKK];
  const int bl = blockIdx.x;           // b*LL + l
  const int b  = bl / LL;
  const int l  = bl - b * LL;
  const int t  = threadIdx.x;
  tok_s[t] = token[(size_t)bl * TKK + t];
  __syncthreads();
  const float4* w2r = (const float4*)(W2 + (size_t)t * TKK);
  const float4* w3r = (const float4*)(W3 + (size_t)t * TKK);
  float a2 = 0.f, a3 = 0.f;
#pragma unroll 8
  for (int i = 0; i < TKK / 4; ++i) {
    float4 x = w2r[i];
    float4 y = w3r[i];
    const float* ts = &tok_s[4 * i];
    a2 += x.x * ts[0] + x.y * ts[1] + x.z * ts[2] + x.w * ts[3];
    a3 += y.x * ts[0] + y.y * ts[1] + y.z * ts[2] + y.w * ts[3];
  }
  tq_s[t] = a2;
  t3t[((size_t)b * CCH + t) * 20 + l] = a3 + b3[t];
  __syncthreads();
  float s0 = 0.f, s1 = 0.f, s2 = 0.f, s3 = 0.f;
#pragma unroll 4
  for (int k = 0; k < TKK; k += 4) {
    s0 += W1[(k + 0) * CCH + t] * tq_s[k + 0];
    s1 += W1[(k + 1) * CCH + t] * tq_s[k + 1];
    s2 += W1[(k + 2) * CCH + t] * tq_s[k + 2];
    s3 += W1[(k + 3) * CCH + t] * tq_s[k + 3];
  }
  u[(size_t)bl * CCH + t] = (s0 + s1 + s2 + s3) * (1.0f / 64.0f);
}

// ---------------------------------------------------------------------------
// Main fused kernel. Block = (b, one 128-pixel image row). 256 thr = 4 waves.
// Wave wv owns channel slice [wv*64, wv*64+64); lane owns pixel pair (2i,2i+1)
// -> float2 global loads; the pair shares one nearest-upsampled mask value.
// __launch_bounds__(256,2): R2's (256,4) forced a 64-VGPR budget -> scratch
// spills (WRITE_SIZE 131->199 MB) that serialized the inner loop. Live state
// needs ~90 VGPRs (facc[19][2]=38 / p[19][2]=38 + loads); (256,2) removes the
// spills; occupancy stays ~4 blocks/CU via LDS (29 KB) + actual VGPR use.
// ---------------------------------------------------------------------------
__global__ __launch_bounds__(256, 2) void k_main(
    const float* __restrict__ mask, const float* __restrict__ fea,
    const float* __restrict__ u, const float* __restrict__ t3t,
    float* __restrict__ out) {
  __shared__ float u_s[LL][CCH];     // [l][c]
  __shared__ float acc_s[LL][128];   // logits -> probs, [l][pix]

  const int blk  = blockIdx.x;
  const int b    = blk & 7;          // b fastest: blocks sharing fea adjacent
  const int tile = blk >> 3;         // 0..127 = image row
  const int n0   = tile * WW;
  const int t    = threadIdx.x;
  const int lane = t & 63;
  const int wv   = t >> 6;

  // stage u (coalesced) + zero the accumulator
#pragma unroll
  for (int l = 0; l < LL; ++l) u_s[l][t] = u[((size_t)b * LL + l) * CCH + t];
  for (int k = t; k < LL * 128; k += 256) ((float*)acc_s)[k] = 0.f;

  // mask value shared by the lane's pixel pair: row tile/2, col lane
  const int hrow = tile >> 1;
  const float m0 = mask[(((size_t)(b * CLS + 0)) * MHH + hrow) * MWW + lane];
  const float m1 = mask[(((size_t)(b * CLS + 1)) * MHH + hrow) * MWW + lane];
  const float m2 = mask[(((size_t)(b * CLS + 2)) * MHH + hrow) * MWW + lane];
  const float m3 = mask[(((size_t)(b * CLS + 3)) * MHH + hrow) * MWW + lane];

  __syncthreads();

  // fea batch indices: (4b+cl) % 8 == 4*(b&1) + cl
  const int f0 = (b & 1) * 4;
  const float* fb0 = fea + (size_t)(f0 + 0) * CCH * HWSZ + n0;
  const float* fb1 = fea + (size_t)(f0 + 1) * CCH * HWSZ + n0;
  const float* fb2 = fea + (size_t)(f0 + 2) * CCH * HWSZ + n0;
  const float* fb3 = fea + (size_t)(f0 + 3) * CCH * HWSZ + n0;

  float facc[LL][2];
#pragma unroll
  for (int l = 0; l < LL; ++l) { facc[l][0] = 0.f; facc[l][1] = 0.f; }

  const int c0 = wv * 64;
#pragma unroll 2
  for (int cc = 0; cc < 64; cc += 4) {
    float2 q[4];
#pragma unroll
    for (int j = 0; j < 4; ++j) {
      const size_t coff = (size_t)(c0 + cc + j) * HWSZ;
      const float2 v0 = ((const float2*)(fb0 + coff))[lane];
      const float2 v1 = ((const float2*)(fb1 + coff))[lane];
      const float2 v2 = ((const float2*)(fb2 + coff))[lane];
      const float2 v3 = ((const float2*)(fb3 + coff))[lane];
      q[j].x = v0.x * m0 + v1.x * m1 + v2.x * m2 + v3.x * m3;
      q[j].y = v0.y * m0 + v1.y * m1 + v2.y * m2 + v3.y * m3;
    }
#pragma unroll
    for (int l = 0; l < LL; ++l) {
      const float4 uu = *(const float4*)&u_s[l][c0 + cc];  // uniform broadcast
      facc[l][0] += q[0].x * uu.x + q[1].x * uu.y + q[2].x * uu.z + q[3].x * uu.w;
      facc[l][1] += q[0].y * uu.x + q[1].y * uu.y + q[2].y * uu.z + q[3].y * uu.w;
    }
  }

  // cross-wave reduction: distinct addresses within a wave, 4-way across waves
#pragma unroll
  for (int l = 0; l < LL; ++l) {
    atomicAdd(&acc_s[l][2 * lane + 0], facc[l][0]);
    atomicAdd(&acc_s[l][2 * lane + 1], facc[l][1]);
  }
  __syncthreads();

  // softmax over l, in-place (threads 0..127, one pixel each; stride-1 = free)
  if (t < 128) {
    float a[LL];
    float mx = -INFINITY;
#pragma unroll
    for (int l = 0; l < LL; ++l) { a[l] = acc_s[l][t]; mx = fmaxf(mx, a[l]); }
    float e[LL];
    float sum = 0.f;
#pragma unroll
    for (int l = 0; l < LL; ++l) { e[l] = __expf(a[l] - mx); sum += e[l]; }
    const float inv = 1.0f / sum;
#pragma unroll
    for (int l = 0; l < LL; ++l)
      acc_s[l][t] = (a[l] != 0.f) ? e[l] * inv : 0.f;  // replicate where(a!=0)
  }
  __syncthreads();

  // probs for this lane's pixel pair
  float2 p[LL];
#pragma unroll
  for (int l = 0; l < LL; ++l) p[l] = *(const float2*)&acc_s[l][2 * lane];

  // phase 4: wave-uniform o-slice; t3 rows via scalar loads
  const int wvu = __builtin_amdgcn_readfirstlane(wv);
  const int ob  = wvu * 64;
#pragma unroll 4
  for (int i = 0; i < 64; ++i) {
    const int o = ob + i;
    const float* tr = t3t + ((size_t)b * CCH + o) * 20;  // uniform -> s_load
    float sx = 0.f, sy = 0.f;
#pragma unroll
    for (int l = 0; l < LL; ++l) {
      const float tv = tr[l];
      sx += p[l].x * tv;
      sy += p[l].y * tv;
    }
    const size_t off = ((size_t)b * CCH + o) * HWSZ + n0;
    const float2 r = ((const float2*)(fea + off))[lane];
    float2 res;
    res.x = sx + r.x;
    res.y = sy + r.y;
    ((float2*)(out + off))[lane] = res;
  }
}

// ---------------------------------------------------------------------------
extern "C" void kernel_launch(void* const* d_in, const int* in_sizes, int n_in,
                              void* d_out, int out_size, void* d_ws, size_t ws_size,
                              hipStream_t stream) {
  (void)in_sizes; (void)n_in; (void)out_size; (void)ws_size;
  const float* mask  = (const float*)d_in[0];
  const float* fea   = (const float*)d_in[1];
  const float* token = (const float*)d_in[2];
  const float* W1    = (const float*)d_in[3];
  const float* W2    = (const float*)d_in[4];
  const float* W3    = (const float*)d_in[5];
  const float* b3    = (const float*)d_in[6];
  float* out = (float*)d_out;

  float* u   = (float*)d_ws;                 // BS*LL*CCH floats (38912)
  float* t3t = u + BS * LL * CCH;            // BS*CCH*20 floats (40960)

  k_prep<<<BS * LL, 256, 0, stream>>>(token, W1, W2, W3, b3, u, t3t);
  k_main<<<(HWSZ / WW) * BS, 256, 0, stream>>>(mask, fea, u, t3t, out);
}